// Round 3
// baseline (144.158 us; speedup 1.0000x reference)
//
#include <hip/hip_runtime.h>

#define BLOCK 256
#define FT 1024           // output elements per tile (final kernel)
#define PSTRIDE 32        // persistent grid.x: each block does 256/32 = 8 tiles

// Barrier WITHOUT vmcnt drain: LDS visibility needs lgkmcnt only. Keeps the
// prefetch global loads in flight across phase barriers (the __syncthreads
// vmcnt(0) drain was exposing ~900cy of load latency per tile).
#define BAR_LGKM() do { \
    asm volatile("s_waitcnt lgkmcnt(0)" ::: "memory"); \
    __builtin_amdgcn_s_barrier(); \
} while (0)

static __device__ __forceinline__ float ldz(const float* __restrict__ p, int i, int n) {
    return (i >= 0 && i < n) ? p[i] : 0.f;
}

// Quad-filter taps, reversed/deinterleaved, sqrt2 folded into the highpass set.
struct QFilt {
    float b0e[5], b0o[5], a0e[5], a0o[5];
    float b1e[5], b1o[5], a1e[5], a1o[5];
};

static __device__ __forceinline__ QFilt load_qfilt(
    const float* __restrict__ g0a, const float* __restrict__ g0b,
    const float* __restrict__ g1a, const float* __restrict__ g1b) {
    const float S2 = 1.4142135623730951f;
    QFilt f;
#pragma unroll
    for (int i = 0; i < 5; ++i) {
        f.b0e[i] = g0b[8 - 2 * i]; f.b0o[i] = g0b[9 - 2 * i];
        f.a0e[i] = g0a[8 - 2 * i]; f.a0o[i] = g0a[9 - 2 * i];
        f.b1e[i] = S2 * g1b[8 - 2 * i]; f.b1o[i] = S2 * g1b[9 - 2 * i];
        f.a1e[i] = S2 * g1a[8 - 2 * i]; f.a1o[i] = S2 * g1a[9 - 2 * i];
    }
    return f;
}

// Quad out[4s..4s+3], lo window consecutive in LDS starting at lobase
// (lo_s[lobase+g] = lo[2s-4+g], g=0..9); r/i stride-1 windows at ribase.
static __device__ __forceinline__ float4 quad_i(
    const float* __restrict__ lo_s, int lobase,
    const float* __restrict__ r_s, const float* __restrict__ i_s, int ribase,
    const QFilt& f) {
    float y0 = 0.f, y1 = 0.f, y2 = 0.f, y3 = 0.f;
#pragma unroll
    for (int i = 0; i < 5; ++i) {
        float ve = lo_s[lobase + 2 * i], vo = lo_s[lobase + 2 * i + 1];
        float vr = r_s[ribase + i], vi = i_s[ribase + i];
        y0 = fmaf(ve, f.b0e[i], y0); y2 = fmaf(ve, f.b0o[i], y2);
        y1 = fmaf(vo, f.a0e[i], y1); y3 = fmaf(vo, f.a0o[i], y3);
        y0 = fmaf(vr, f.b1e[i], y0); y2 = fmaf(vr, f.b1o[i], y2);
        y1 = fmaf(vi, f.a1e[i], y1); y3 = fmaf(vi, f.a1o[i], y3);
    }
    return make_float4(y0, y1, y2, y3);
}

// Quad with lo window DEINTERLEAVED: Ae[base+i]=lo[2s-4+2i], Ao[base+i]=lo[2s-3+2i].
static __device__ __forceinline__ float4 quad_d(
    const float* __restrict__ Ae, const float* __restrict__ Ao, int base,
    const float* __restrict__ r_s, const float* __restrict__ i_s, int ribase,
    const QFilt& f) {
    float y0 = 0.f, y1 = 0.f, y2 = 0.f, y3 = 0.f;
#pragma unroll
    for (int i = 0; i < 5; ++i) {
        float ve = Ae[base + i], vo = Ao[base + i];
        float vr = r_s[ribase + i], vi = i_s[ribase + i];
        y0 = fmaf(ve, f.b0e[i], y0); y2 = fmaf(ve, f.b0o[i], y2);
        y1 = fmaf(vo, f.a0e[i], y1); y3 = fmaf(vo, f.a0o[i], y3);
        y0 = fmaf(vr, f.b1e[i], y0); y2 = fmaf(vr, f.b1o[i], y2);
        y1 = fmaf(vi, f.a1e[i], y1); y3 = fmaf(vi, f.a1o[i], y3);
    }
    return make_float4(y0, y1, y2, y3);
}

// TWO fused coarse levels (R11 structure, unchanged — measured near floor).
__global__ void __launch_bounds__(BLOCK) pair_lvl(
    const float* __restrict__ up,
    const float* __restrict__ ru, const float* __restrict__ iu,
    const float* __restrict__ rl, const float* __restrict__ il,
    float* __restrict__ out,
    const float* __restrict__ g0a, const float* __restrict__ g0b,
    const float* __restrict__ g1a, const float* __restrict__ g1b,
    int L)
{
    __shared__ __align__(16) float upw[272], ruw[140], iuw[140], rlw[264], ilw[264];
    __shared__ __align__(16) float Ae[260], Ao[260];
    int tid = threadIdx.x, bx = blockIdx.x, row = blockIdx.y;
    int lup = L >> 2, lu8 = L >> 3, lql = L >> 2;
    const float* uprow = up + (size_t)row * lup;
    const float* rurow = ru + (size_t)row * lu8;
    const float* iurow = iu + (size_t)row * lu8;
    const float* rlrow = rl + (size_t)row * lql;
    const float* ilrow = il + (size_t)row * lql;
    bool bnd = (bx == 0) || (bx == (int)gridDim.x - 1);
    int S = bx << 8;
    int sAu = (S >> 1) - 1;
    int gu = S - 8;
    int gru = (S >> 1) - 4;
    int grl = S - 4;

    for (int i = tid; i < 270; i += BLOCK) {
        const float* src; float* dst; int k, gb, len;
        if (i < 68)       { src = uprow; dst = upw; k = i;       gb = gu + 4 * k;  len = lup; }
        else if (i < 103) { src = rurow; dst = ruw; k = i - 68;  gb = gru + 4 * k; len = lu8; }
        else if (i < 138) { src = iurow; dst = iuw; k = i - 103; gb = gru + 4 * k; len = lu8; }
        else if (i < 204) { src = rlrow; dst = rlw; k = i - 138; gb = grl + 4 * k; len = lql; }
        else              { src = ilrow; dst = ilw; k = i - 204; gb = grl + 4 * k; len = lql; }
        float4 v;
        if (!bnd) v = *reinterpret_cast<const float4*>(src + gb);
        else { v.x = ldz(src, gb, len); v.y = ldz(src, gb + 1, len);
               v.z = ldz(src, gb + 2, len); v.w = ldz(src, gb + 3, len); }
        *reinterpret_cast<float4*>(dst + 4 * k) = v;
    }
    __syncthreads();

    QFilt f = load_qfilt(g0a, g0b, g1a, g1b);
    if (tid < 130) {
        float4 q = quad_i(upw, 2 * tid + 2, ruw, iuw, tid + 1, f);
        if (bnd) {
            int sp = sAu + tid;
            if (sp < 0 || sp >= lu8) q = make_float4(0.f, 0.f, 0.f, 0.f);
        }
        Ae[2 * tid] = q.x; Ae[2 * tid + 1] = q.z;
        Ao[2 * tid] = q.y; Ao[2 * tid + 1] = q.w;
    }
    __syncthreads();

    float4 res = quad_d(Ae, Ao, tid, rlw, ilw, tid + 2, f);
    reinterpret_cast<float4*>(out + (size_t)row * L)[S + tid] = res;
}

// R15: persistent 4-level final. Each block iterates 8 tiles (stride PSTRIDE);
// next tile's staging + epilogue loads are issued into REGISTERS right after
// the stage barrier, so their HBM latency hides under phases A..D of the
// current tile. Barriers are lgkm-only (BAR_LGKM) so prefetch loads are NOT
// drained at phase barriers (the __syncthreads vmcnt(0) drain was the stall).
__global__ void __launch_bounds__(BLOCK) final4_persist(
    const float* __restrict__ x4,                                 // T/8 per row
    const float* __restrict__ r3, const float* __restrict__ i3,   // T/16 per row
    const float* __restrict__ r2, const float* __restrict__ i2,   // T/8 per row
    const float* __restrict__ r1, const float* __restrict__ i1,   // T/4 per row
    const float* __restrict__ r0, const float* __restrict__ i0,   // T/2 per row
    float* __restrict__ out,                                      // T per row
    const float* __restrict__ g0a, const float* __restrict__ g0b,
    const float* __restrict__ g1a, const float* __restrict__ g1b,
    const float* __restrict__ g0o, const float* __restrict__ g1o,
    int T_)
{
    const float S2 = 1.4142135623730951f;
    __shared__ __align__(16) float x4w[152], r3w[80], i3w[80];
    __shared__ __align__(16) float r2w[144], i2w[144];
    __shared__ __align__(16) float r1w[264], i1w[264];
    __shared__ __align__(16) float x3s[280], x2s[528];
    __shared__ __align__(16) float4 x1q[258];

    int row = blockIdx.y, tid = threadIdx.x;
    int t2 = T_ >> 1, t4 = T_ >> 2, t8 = T_ >> 3, t16 = T_ >> 4;
    int NT = T_ >> 10;   // tiles per row (FT = 1024)
    const float* x4row = x4 + (size_t)row * t8;
    const float* r3row = r3 + (size_t)row * t16;
    const float* i3row = i3 + (size_t)row * t16;
    const float* r2row = r2 + (size_t)row * t8;
    const float* i2row = i2 + (size_t)row * t8;
    const float* r1row = r1 + (size_t)row * t4;
    const float* i1row = i1 + (size_t)row * t4;
    const float* r0row = r0 + (size_t)row * t2;
    const float* i0row = i0 + (size_t)row * t2;

    // ---- tile-invariant staging slot mapping.
    // slot0: i = tid (< 277 always). gb(tile) = A0*tile + C0.
    // bases: x4: 2*v0-8 = 128t-8 | r3/i3: v0-4 = 64t-4 | r2/i2: u0-4 = 128t-4
    //        r1/i1: s0-4 = 256t-4
    const float* src0; float* dst0; int A0, C0, len0;
    {
        int i = tid, k;
        if (i < 37)       { src0 = x4row; k = i;       dst0 = x4w + 4 * k; A0 = 128; C0 = -8 + 4 * k; len0 = t8; }
        else if (i < 56)  { src0 = r3row; k = i - 37;  dst0 = r3w + 4 * k; A0 = 64;  C0 = -4 + 4 * k; len0 = t16; }
        else if (i < 75)  { src0 = i3row; k = i - 56;  dst0 = i3w + 4 * k; A0 = 64;  C0 = -4 + 4 * k; len0 = t16; }
        else if (i < 110) { src0 = r2row; k = i - 75;  dst0 = r2w + 4 * k; A0 = 128; C0 = -4 + 4 * k; len0 = t8; }
        else if (i < 145) { src0 = i2row; k = i - 110; dst0 = i2w + 4 * k; A0 = 128; C0 = -4 + 4 * k; len0 = t8; }
        else if (i < 211) { src0 = r1row; k = i - 145; dst0 = r1w + 4 * k; A0 = 256; C0 = -4 + 4 * k; len0 = t4; }
        else              { src0 = i1row; k = i - 211; dst0 = i1w + 4 * k; A0 = 256; C0 = -4 + 4 * k; len0 = t4; }
    }
    // slot1: i = tid + 256 (valid tid < 21) — always lands in i1w.
    bool has1 = (tid < 21);
    int k1 = tid + 45;                       // (tid+256) - 211
    float* dst1 = i1w + 4 * k1;
    int C1 = -4 + 4 * k1;                    // gb1 = 256*tile + C1

    QFilt f = load_qfilt(g0a, g0b, g1a, g1b);
    float g0r[7], g1r[5];
#pragma unroll
    for (int j = 0; j < 7; ++j) g0r[j] = g0o[j];
#pragma unroll
    for (int j = 0; j < 5; ++j) g1r[j] = S2 * g1o[j];

    // ---- initial prefetch (tile = blockIdx.x) ----
    int tile = blockIdx.x;
    bool bndc = (tile == 0) || (tile == NT - 1);
    float4 pv0, pv1 = make_float4(0.f, 0.f, 0.f, 0.f);
    {
        int gb = A0 * tile + C0;
        if (!bndc) pv0 = *reinterpret_cast<const float4*>(src0 + gb);
        else { pv0.x = ldz(src0, gb, len0); pv0.y = ldz(src0, gb + 1, len0);
               pv0.z = ldz(src0, gb + 2, len0); pv0.w = ldz(src0, gb + 3, len0); }
        if (has1) {
            int gb1 = 256 * tile + C1;
            if (!bndc) pv1 = *reinterpret_cast<const float4*>(i1row + gb1);
            else { pv1.x = ldz(i1row, gb1, t4); pv1.y = ldz(i1row, gb1 + 1, t4);
                   pv1.z = ldz(i1row, gb1 + 2, t4); pv1.w = ldz(i1row, gb1 + 3, t4); }
        }
    }
    float4 prA_c, piA_c, prA_n = make_float4(0,0,0,0), piA_n = make_float4(0,0,0,0);
    {
        int u0e = (tile << 9) + 2 * tid - 1;
        if (!bndc) {
            prA_c = *reinterpret_cast<const float4*>(r0row + u0e);
            piA_c = *reinterpret_cast<const float4*>(i0row + u0e);
        } else {
            prA_c.x = ldz(r0row, u0e, t2);     prA_c.y = ldz(r0row, u0e + 1, t2);
            prA_c.z = ldz(r0row, u0e + 2, t2); prA_c.w = ldz(r0row, u0e + 3, t2);
            piA_c.x = ldz(i0row, u0e, t2);     piA_c.y = ldz(i0row, u0e + 1, t2);
            piA_c.z = ldz(i0row, u0e + 2, t2); piA_c.w = ldz(i0row, u0e + 3, t2);
        }
    }

    bool bndn = false;
    while (true) {
        // ---- stage write (regs -> LDS; compiler inserts the vmcnt wait) ----
        *reinterpret_cast<float4*>(dst0) = pv0;
        if (has1) *reinterpret_cast<float4*>(dst1) = pv1;
        BAR_LGKM();

        // ---- prefetch NEXT tile (issued now; consumed next iteration) ----
        int ntile = tile + PSTRIDE;
        bool nvalid = ntile < NT;
        if (nvalid) {
            bndn = (ntile == NT - 1);   // ntile > 0 always
            int gb = A0 * ntile + C0;
            if (!bndn) pv0 = *reinterpret_cast<const float4*>(src0 + gb);
            else { pv0.x = ldz(src0, gb, len0); pv0.y = ldz(src0, gb + 1, len0);
                   pv0.z = ldz(src0, gb + 2, len0); pv0.w = ldz(src0, gb + 3, len0); }
            if (has1) {
                int gb1 = 256 * ntile + C1;
                if (!bndn) pv1 = *reinterpret_cast<const float4*>(i1row + gb1);
                else { pv1.x = ldz(i1row, gb1, t4); pv1.y = ldz(i1row, gb1 + 1, t4);
                       pv1.z = ldz(i1row, gb1 + 2, t4); pv1.w = ldz(i1row, gb1 + 3, t4); }
            }
            int u0e = (ntile << 9) + 2 * tid - 1;
            if (!bndn) {
                prA_n = *reinterpret_cast<const float4*>(r0row + u0e);
                piA_n = *reinterpret_cast<const float4*>(i0row + u0e);
            } else {
                prA_n.x = ldz(r0row, u0e, t2);     prA_n.y = ldz(r0row, u0e + 1, t2);
                prA_n.z = ldz(r0row, u0e + 2, t2); prA_n.w = ldz(r0row, u0e + 3, t2);
                piA_n.x = ldz(i0row, u0e, t2);     piA_n.y = ldz(i0row, u0e + 1, t2);
                piA_n.z = ldz(i0row, u0e + 2, t2); piA_n.w = ldz(i0row, u0e + 3, t2);
            }
        }

        int s0 = tile << 8, u0 = tile << 7, v0 = tile << 6;

        // ---- phase A: 69 x3-quads ----
        if (tid < 69) {
            int k = tid;
            float4 q = quad_i(x4w, 2 * k, r3w, i3w, k, f);
            if (bndc) {
                int v = v0 - 2 + k;
                if (v < 0 || v >= t16) q = make_float4(0.f, 0.f, 0.f, 0.f);
            }
            reinterpret_cast<float4*>(x3s)[k] = q;
        }
        BAR_LGKM();

        // ---- phase B: 132 x2-quads ----
        if (tid < 132) {
            int k = tid;
            float4 q = quad_i(x3s, 2 * k, r2w, i2w, k, f);
            if (bndc) {
                int u = u0 - 2 + k;
                if (u < 0 || u >= t8) q = make_float4(0.f, 0.f, 0.f, 0.f);
            }
            reinterpret_cast<float4*>(x2s)[k] = q;
        }
        BAR_LGKM();

        // ---- phase C: 258 x1-quads ----
        float4 myq;
        {
            int l = tid;
            float4 q = quad_i(x2s, 2 * l + 2, r1w, i1w, l + 1, f);
            if (bndc) {
                int s = s0 - 1 + l;
                if (s < 0 || s >= t4) q = make_float4(0.f, 0.f, 0.f, 0.f);
            }
            myq = q;
            x1q[l] = q;
            if (tid < 2) {
                int l2 = 256 + tid;
                q = quad_i(x2s, 2 * l2 + 2, r1w, i1w, l2 + 1, f);
                if (bndc) {
                    int s = s0 - 1 + l2;
                    if (s < 0 || s >= t4) q = make_float4(0.f, 0.f, 0.f, 0.f);
                }
                x1q[l2] = q;
            }
        }
        BAR_LGKM();

        // ---- phase D: epilogue ----
        float w[12];
        *reinterpret_cast<float4*>(&w[0]) = myq;
        *reinterpret_cast<float4*>(&w[4]) = x1q[tid + 1];
        *reinterpret_cast<float4*>(&w[8]) = x1q[tid + 2];

        float rAv[4] = { prA_c.x, prA_c.y, prA_c.z, prA_c.w };
        float iAv[4] = { piA_c.x, piA_c.y, piA_c.z, piA_c.w };

        float o[4];
#pragma unroll
        for (int p = 0; p < 4; ++p) {
            float acc = 0.f;
#pragma unroll
            for (int j = 0; j < 7; ++j)          // x1[n+3-j] -> w[p+7-j]
                acc = fmaf(g0r[j], w[p + 7 - j], acc);
#pragma unroll
            for (int j = 0; j < 5; ++j) {        // hi0[n+2-j] -> e = p+4-j
                int e = p + 4 - j;
                float v = (e & 1) ? iAv[e >> 1] : rAv[e >> 1];
                acc = fmaf(g1r[j], v, acc);
            }
            o[p] = acc;
        }
        reinterpret_cast<float4*>(out + (size_t)row * T_)[s0 + tid] =
            make_float4(o[0], o[1], o[2], o[3]);

        if (!nvalid) break;
        tile = ntile; bndc = bndn;
        prA_c = prA_n; piA_c = piA_n;
    }
}

extern "C" void kernel_launch(void* const* d_in, const int* in_sizes, int n_in,
                              void* d_out, int out_size, void* d_ws, size_t ws_size,
                              hipStream_t stream)
{
    const float* yl = (const float*)d_in[0];
    const float* yhr[8]; const float* yhi[8];
    for (int j = 0; j < 8; ++j) {
        yhr[j] = (const float*)d_in[1 + 2 * j];
        yhi[j] = (const float*)d_in[2 + 2 * j];
    }
    const float* g0o = (const float*)d_in[17];
    const float* g1o = (const float*)d_in[18];
    const float* g0a = (const float*)d_in[19];
    const float* g0b = (const float*)d_in[20];
    const float* g1a = (const float*)d_in[21];
    const float* g1b = (const float*)d_in[22];

    const int BC = 32 * 4;
    const int T_ = 262144;

    // Scratch: final4 reads x4 while writing the FULL d_out, so x4/x6 live in ws.
    float* x4buf = (float*)d_ws;
    float* x6buf = (float*)((char*)d_ws + ((size_t)32 << 20));

    // K76: yl + yh7 + yh6 -> x6 (L = 8192)
    {
        dim3 grid(8192 / 1024, BC);
        pair_lvl<<<grid, BLOCK, 0, stream>>>(
            yl, yhr[7], yhi[7], yhr[6], yhi[6], x6buf,
            g0a, g0b, g1a, g1b, 8192);
    }
    // K54: x6 + yh5 + yh4 -> x4 (L = 32768)
    {
        dim3 grid(32768 / 1024, BC);
        pair_lvl<<<grid, BLOCK, 0, stream>>>(
            x6buf, yhr[5], yhi[5], yhr[4], yhi[4], x4buf,
            g0a, g0b, g1a, g1b, 32768);
    }
    // final4_persist: x4 + yh3 + yh2 + yh1 + yh0 -> out, 8 tiles/block.
    dim3 grid(PSTRIDE, BC);
    final4_persist<<<grid, BLOCK, 0, stream>>>(
        x4buf, yhr[3], yhi[3], yhr[2], yhi[2], yhr[1], yhi[1],
        yhr[0], yhi[0], (float*)d_out,
        g0a, g0b, g1a, g1b, g0o, g1o, T_);
}